// Round 1
// baseline (290.595 us; speedup 1.0000x reference)
//
#include <hip/hip_runtime.h>
#include <hip/hip_bf16.h>

// Problem constants (B=4, T=4096, C=1024, H=128)
#define T_SEQ 4096
#define NBATCH 4
#define C_EMB 1024
#define H_DIM 128
#define M_ROWS (NBATCH * T_SEQ)   // 16384

typedef __bf16 bf16x8 __attribute__((ext_vector_type(8)));
typedef float  floatx4 __attribute__((ext_vector_type(4)));

__device__ __forceinline__ ushort f2bf(float f) {
    __hip_bfloat16 h = __float2bfloat16(f);
    return *reinterpret_cast<ushort*>(&h);
}
__device__ __forceinline__ float bf2f(ushort u) {
    unsigned int v = ((unsigned int)u) << 16;
    return *reinterpret_cast<float*>(&v);
}

// ---------------------------------------------------------------------------
// Kernel 0: transpose weights fp32 [C][H] -> bf16 Wt[z][H][K=C] so the GEMM's
// B-operand fragments (B[k][n], k contiguous per lane) read k-contiguous rows.
// grid (64, 3) x 256 threads; each thread packs 8 k's for one n.
// ---------------------------------------------------------------------------
__global__ __launch_bounds__(256) void transpose_w(
    const float* __restrict__ Wk, const float* __restrict__ Wq,
    const float* __restrict__ Wv, ushort* __restrict__ wt) {
    const int z = blockIdx.y;
    const float* W = (z == 0) ? Wk : (z == 1) ? Wq : Wv;
    ushort* Wtz = wt + (size_t)z * H_DIM * C_EMB;
    int linear = blockIdx.x * 256 + threadIdx.x;       // [0, 16384)
    int n  = linear >> 7;                              // 0..127
    int k0 = (linear & 127) << 3;                      // 0..1016 step 8
    ushort tmp[8];
#pragma unroll
    for (int j = 0; j < 8; ++j)
        tmp[j] = f2bf(W[(size_t)(k0 + j) * H_DIM + n]);
    uint4 pk;
    pk.x = (uint)tmp[0] | ((uint)tmp[1] << 16);
    pk.y = (uint)tmp[2] | ((uint)tmp[3] << 16);
    pk.z = (uint)tmp[4] | ((uint)tmp[5] << 16);
    pk.w = (uint)tmp[6] | ((uint)tmp[7] << 16);
    *reinterpret_cast<uint4*>(Wtz + (size_t)n * C_EMB + k0) = pk;
}

// ---------------------------------------------------------------------------
// Kernel 1: QKV GEMM. Y[z] = x @ W[z], output bf16 into ws kqv[z][16384][128].
// 128x128 block tile, BK=32, mfma_f32_16x16x32_bf16. z==0 (k, the query role)
// is pre-scaled by C^-0.5 = 1/32 in the epilogue.
// grid (128, 3) x 256 threads (4 waves; wave w owns rows w*32..w*32+31).
// ---------------------------------------------------------------------------
#define AS_STRIDE 40   // 32 + 8 pad (bf16); row pitch 80B = 16B*5 (aligned)
__global__ __launch_bounds__(256) void qkv_gemm(
    const float* __restrict__ x, const ushort* __restrict__ wt,
    ushort* __restrict__ kqv) {
    const int z  = blockIdx.y;
    const int m0 = blockIdx.x * 128;
    const ushort* Wtz = wt + (size_t)z * H_DIM * C_EMB;

    __shared__ ushort As[128 * AS_STRIDE];
    __shared__ ushort Bs[128 * AS_STRIDE];

    const int tid  = threadIdx.x;
    const int lane = tid & 63;
    const int wave = tid >> 6;
    const int l15  = lane & 15;
    const int quad = lane >> 4;

    floatx4 acc[2][8];
#pragma unroll
    for (int mi = 0; mi < 2; ++mi)
#pragma unroll
        for (int ni = 0; ni < 8; ++ni)
            acc[mi][ni] = floatx4{0.f, 0.f, 0.f, 0.f};

    for (int kt = 0; kt < C_EMB / 32; ++kt) {
        __syncthreads();
        // stage A: x tile [128 rows][32 k] fp32 -> bf16 (coalesced float4)
#pragma unroll
        for (int i = 0; i < 4; ++i) {
            int f4 = i * 256 + tid;            // 0..1023 float4s
            int r  = f4 >> 3;
            int c4 = (f4 & 7) << 2;            // col in floats
            float4 v = *reinterpret_cast<const float4*>(
                x + (size_t)(m0 + r) * C_EMB + kt * 32 + c4);
            __hip_bfloat162 h0 = __float22bfloat162_rn(make_float2(v.x, v.y));
            __hip_bfloat162 h1 = __float22bfloat162_rn(make_float2(v.z, v.w));
            ushort4 h;
            h.x = *reinterpret_cast<ushort*>(&h0.x);
            h.y = *(reinterpret_cast<ushort*>(&h0.x) + 1);
            h.z = *reinterpret_cast<ushort*>(&h1.x);
            h.w = *(reinterpret_cast<ushort*>(&h1.x) + 1);
            *reinterpret_cast<ushort4*>(As + r * AS_STRIDE + c4) = h;
        }
        // stage B: Wt tile [128 n][32 k] bf16, already k-contiguous
#pragma unroll
        for (int i = 0; i < 2; ++i) {
            int u   = i * 256 + tid;           // 0..511 (8-bf16 units)
            int n   = u >> 2;
            int seg = (u & 3) << 3;
            uint4 v = *reinterpret_cast<const uint4*>(
                Wtz + (size_t)n * C_EMB + kt * 32 + seg);
            *reinterpret_cast<uint4*>(Bs + n * AS_STRIDE + seg) = v;
        }
        __syncthreads();

        bf16x8 a0 = *reinterpret_cast<const bf16x8*>(
            As + (wave * 32 + l15) * AS_STRIDE + quad * 8);
        bf16x8 a1 = *reinterpret_cast<const bf16x8*>(
            As + (wave * 32 + 16 + l15) * AS_STRIDE + quad * 8);
#pragma unroll
        for (int ni = 0; ni < 8; ++ni) {
            bf16x8 b = *reinterpret_cast<const bf16x8*>(
                Bs + (ni * 16 + l15) * AS_STRIDE + quad * 8);
            acc[0][ni] = __builtin_amdgcn_mfma_f32_16x16x32_bf16(a0, b, acc[0][ni], 0, 0, 0);
            acc[1][ni] = __builtin_amdgcn_mfma_f32_16x16x32_bf16(a1, b, acc[1][ni], 0, 0, 0);
        }
    }

    const float scale = (z == 0) ? 0.03125f : 1.0f;   // fold C^-0.5 into k
    ushort* outz = kqv + (size_t)z * M_ROWS * H_DIM;
#pragma unroll
    for (int mi = 0; mi < 2; ++mi)
#pragma unroll
        for (int ni = 0; ni < 8; ++ni)
#pragma unroll
            for (int r = 0; r < 4; ++r) {
                int row = m0 + wave * 32 + mi * 16 + quad * 4 + r;
                int col = ni * 16 + l15;
                outz[(size_t)row * H_DIM + col] = f2bf(acc[mi][ni][r] * scale);
            }
}

// ---------------------------------------------------------------------------
// Kernel 2: causal flash attention. Q-role = k (pre-scaled), K-role = q, V = v.
// BM=BN=64, block = 256 threads (4 waves, 16 Q-rows each). Online softmax.
// grid (64, 4): x -> Q-tile (paired heavy/light), y -> batch.
// ---------------------------------------------------------------------------
#define QK_STRIDE 136  // 128 + 8 pad; row pitch 272B = 16B*17
#define VT_STRIDE 72   // 64 + 8 pad; row pitch 144B = 16B*9
__global__ __launch_bounds__(256) void flash_attn(
    const ushort* __restrict__ kqv, float* __restrict__ out) {
    const int b  = blockIdx.y;
    const int xx = blockIdx.x;
    const int it = (xx & 1) ? (xx >> 1) : (63 - (xx >> 1));  // heavy/light pair
    const int i0 = it * 64;

    const size_t bbase = (size_t)b * T_SEQ * H_DIM;
    const ushort* Qg = kqv + bbase;                              // k proj (query role)
    const ushort* Kg = kqv + (size_t)M_ROWS * H_DIM + bbase;     // q proj (key role)
    const ushort* Vg = kqv + (size_t)2 * M_ROWS * H_DIM + bbase; // v proj

    __shared__ ushort Qs[64 * QK_STRIDE];
    __shared__ ushort Ks[64 * QK_STRIDE];
    __shared__ ushort Vt[H_DIM * VT_STRIDE];
    __shared__ ushort Ps[4][16 * VT_STRIDE];

    const int tid  = threadIdx.x;
    const int lane = tid & 63;
    const int wave = tid >> 6;
    const int l15  = lane & 15;
    const int quad = lane >> 4;

    // stage Q tile (once): rows i0..i0+63, natural layout
    {
        int r = tid >> 2, seg = (tid & 3) * 32;
#pragma unroll
        for (int i = 0; i < 4; ++i) {
            uint4 v = *reinterpret_cast<const uint4*>(
                Qg + (size_t)(i0 + r) * H_DIM + seg + i * 8);
            *reinterpret_cast<uint4*>(Qs + r * QK_STRIDE + seg + i * 8) = v;
        }
    }

    float m_i[4], l_i[4];
#pragma unroll
    for (int r = 0; r < 4; ++r) { m_i[r] = -1e30f; l_i[r] = 0.f; }
    floatx4 o[8];
#pragma unroll
    for (int nh = 0; nh < 8; ++nh) o[nh] = floatx4{0.f, 0.f, 0.f, 0.f};

    for (int jt = 0; jt <= it; ++jt) {
        const int j0 = jt * 64;
        __syncthreads();  // previous iter's reads of Ks/Vt done
        // stage K tile: natural layout (n=j rows, k=h contiguous)
        {
            int r = tid >> 2, seg = (tid & 3) * 32;
#pragma unroll
            for (int i = 0; i < 4; ++i) {
                uint4 v = *reinterpret_cast<const uint4*>(
                    Kg + (size_t)(j0 + r) * H_DIM + seg + i * 8);
                *reinterpret_cast<uint4*>(Ks + r * QK_STRIDE + seg + i * 8) = v;
            }
        }
        // stage V tile TRANSPOSED: Vt[h][j]. Lane mapping: per-instr all 64
        // lanes share h, j=0..63 -> contiguous 128B, 2-way b16 conflict (free).
        {
            int j = tid & 63, hb = (tid >> 6) * 32;
#pragma unroll
            for (int i = 0; i < 4; ++i) {
                uint4 v = *reinterpret_cast<const uint4*>(
                    Vg + (size_t)(j0 + j) * H_DIM + hb + i * 8);
                const ushort* pv = reinterpret_cast<const ushort*>(&v);
#pragma unroll
                for (int e = 0; e < 8; ++e)
                    Vt[(hb + i * 8 + e) * VT_STRIDE + j] = pv[e];
            }
        }
        __syncthreads();

        // S = Q K^T  (wave's 16 rows x 64 cols), K-dim = H = 128
        floatx4 s[4];
#pragma unroll
        for (int ni = 0; ni < 4; ++ni) s[ni] = floatx4{0.f, 0.f, 0.f, 0.f};
#pragma unroll
        for (int kk = 0; kk < 4; ++kk) {
            bf16x8 a = *reinterpret_cast<const bf16x8*>(
                Qs + (wave * 16 + l15) * QK_STRIDE + kk * 32 + quad * 8);
#pragma unroll
            for (int ni = 0; ni < 4; ++ni) {
                bf16x8 bb = *reinterpret_cast<const bf16x8*>(
                    Ks + (ni * 16 + l15) * QK_STRIDE + kk * 32 + quad * 8);
                s[ni] = __builtin_amdgcn_mfma_f32_16x16x32_bf16(a, bb, s[ni], 0, 0, 0);
            }
        }

        // causal mask (only the diagonal tile needs it)
        if (jt == it) {
            int ii = i0 + wave * 16 + quad * 4;
#pragma unroll
            for (int ni = 0; ni < 4; ++ni) {
                int j = j0 + ni * 16 + l15;
#pragma unroll
                for (int r = 0; r < 4; ++r)
                    if (j > ii + r) s[ni][r] = -1e30f;
            }
        }

        // online softmax: row stats via 16-lane butterfly (rows = quad*4+r)
        float alpha[4], rs[4];
#pragma unroll
        for (int r = 0; r < 4; ++r) {
            float v = fmaxf(fmaxf(s[0][r], s[1][r]), fmaxf(s[2][r], s[3][r]));
#pragma unroll
            for (int off = 8; off >= 1; off >>= 1)
                v = fmaxf(v, __shfl_xor(v, off, 64));
            float mn = fmaxf(m_i[r], v);
            alpha[r] = __expf(m_i[r] - mn);
            m_i[r] = mn;
            rs[r] = 0.f;
        }
        ushort* Pw = Ps[wave];
#pragma unroll
        for (int ni = 0; ni < 4; ++ni)
#pragma unroll
            for (int r = 0; r < 4; ++r) {
                float p = __expf(s[ni][r] - m_i[r]);
                rs[r] += p;
                Pw[(quad * 4 + r) * VT_STRIDE + ni * 16 + l15] = f2bf(p);
            }
#pragma unroll
        for (int r = 0; r < 4; ++r) {
            float v = rs[r];
#pragma unroll
            for (int off = 8; off >= 1; off >>= 1)
                v += __shfl_xor(v, off, 64);
            l_i[r] = l_i[r] * alpha[r] + v;
        }
#pragma unroll
        for (int nh = 0; nh < 8; ++nh)
#pragma unroll
            for (int r = 0; r < 4; ++r) o[nh][r] *= alpha[r];

        __syncthreads();  // Ps visible (cross-lane within wave) + Vt ready

        // O += P V : A = P (16x64), B = V^T rows (n=h, k=j contiguous)
#pragma unroll
        for (int kp = 0; kp < 2; ++kp) {
            bf16x8 a = *reinterpret_cast<const bf16x8*>(
                Pw + l15 * VT_STRIDE + kp * 32 + quad * 8);
#pragma unroll
            for (int nh = 0; nh < 8; ++nh) {
                bf16x8 bb = *reinterpret_cast<const bf16x8*>(
                    Vt + (nh * 16 + l15) * VT_STRIDE + kp * 32 + quad * 8);
                o[nh] = __builtin_amdgcn_mfma_f32_16x16x32_bf16(a, bb, o[nh], 0, 0, 0);
            }
        }
    }

    // epilogue: normalize by l and store fp32
    float inv[4];
#pragma unroll
    for (int r = 0; r < 4; ++r) inv[r] = 1.0f / l_i[r];
    float* outb = out + ((size_t)b * T_SEQ + i0 + wave * 16) * H_DIM;
#pragma unroll
    for (int nh = 0; nh < 8; ++nh) {
        int col = nh * 16 + l15;
#pragma unroll
        for (int r = 0; r < 4; ++r) {
            int row = quad * 4 + r;
            outb[(size_t)row * H_DIM + col] = o[nh][r] * inv[r];
        }
    }
}

// ---------------------------------------------------------------------------
extern "C" void kernel_launch(void* const* d_in, const int* in_sizes, int n_in,
                              void* d_out, int out_size, void* d_ws, size_t ws_size,
                              hipStream_t stream) {
    const float* x  = (const float*)d_in[0];
    const float* Wk = (const float*)d_in[1];
    const float* Wq = (const float*)d_in[2];
    const float* Wv = (const float*)d_in[3];

    // ws layout (ushort units): kqv[3][16384][128] then Wt[3][128][1024]
    ushort* kqv = (ushort*)d_ws;
    ushort* wt  = kqv + (size_t)3 * M_ROWS * H_DIM;
    // total: (6291456 + 393216) * 2 B = ~12.75 MB of ws

    transpose_w<<<dim3(64, 3), 256, 0, stream>>>(Wk, Wq, Wv, wt);
    qkv_gemm<<<dim3(128, 3), 256, 0, stream>>>(x, wt, kqv);
    flash_attn<<<dim3(64, NBATCH), 256, 0, stream>>>(kqv, (float*)d_out);
}